// Round 1
// baseline (2060.806 us; speedup 1.0000x reference)
//
#include <hip/hip_runtime.h>

#define S_TOT 8192
#define DDIM  64
#define CDIM  256
#define HDIM  1024
#define NSTEPS 8

typedef unsigned short u16;
typedef unsigned int   u32;
typedef __bf16 bf16x8 __attribute__((ext_vector_type(8)));
typedef float  f32x4  __attribute__((ext_vector_type(4)));

typedef __attribute__((address_space(1))) void gvoid_t;
typedef __attribute__((address_space(3))) void lvoid_t;

__device__ __forceinline__ void async_copy16(const void* g, void* l) {
  __builtin_amdgcn_global_load_lds((gvoid_t*)g, (lvoid_t*)l, 16, 0, 0);
}

__device__ __forceinline__ u16 f2bf(float x) {
  union { float f; u32 u; } v; v.f = x;
  u32 r = v.u + 0x7FFFu + ((v.u >> 16) & 1u);
  return (u16)(r >> 16);
}

// ---------------- precompute kernels ----------------

// out[C][R] = bf16(in[R][C])  (transpose + cast), 64x64 tiles via LDS
__global__ __launch_bounds__(256) void k_transpose_cast(
    const float* __restrict__ in, u16* __restrict__ out, int R, int C) {
  __shared__ float t[64][65];
  int tr = blockIdx.x * 64, tc = blockIdx.y * 64;
  int lr = threadIdx.x >> 6;   // 0..3
  int lc = threadIdx.x & 63;
#pragma unroll
  for (int i = 0; i < 16; ++i) {
    int r = i * 4 + lr;
    int gr = tr + r, gc = tc + lc;
    t[r][lc] = (gr < R && gc < C) ? in[(size_t)gr * C + gc] : 0.f;
  }
  __syncthreads();
#pragma unroll
  for (int i = 0; i < 16; ++i) {
    int c = i * 4 + lr;
    int gc = tc + c, gr = tr + lc;
    if (gc < C && gr < R) out[(size_t)gc * R + gr] = f2bf(t[lc][c]);
  }
}

// base1[j] = b1[j] + sum_c ctx[c] * W1[(65+c)*H + j]
__global__ __launch_bounds__(256) void k_base1(
    const float* __restrict__ W1, const float* __restrict__ b1,
    const float* __restrict__ ctx, float* __restrict__ base1) {
  int j = blockIdx.x * 256 + threadIdx.x;
  float s = b1[j];
  for (int c = 0; c < CDIM; ++c)
    s += ctx[c] * W1[(size_t)(DDIM + 1 + c) * HDIM + j];
  base1[j] = s;
}

// ---------------- layer kernels ----------------

// h1[8192,1024] = tanh( (theta + a_h*kbuf) @ W1a + base1 + t_s*W1t )
// A formed on the fly (fp32->bf16) in LDS; B = W1aT [1024][64] bf16.
__global__ __launch_bounds__(256) void k_layer1(
    const float* __restrict__ theta, const float* __restrict__ kbuf,
    const u16* __restrict__ W1aT, const float* __restrict__ W1,
    const float* __restrict__ base1, u16* __restrict__ h1,
    float a_h, float t_s, int use_k) {
  __shared__ u16 Ax[128 * 64];
  __shared__ u16 Bw[128 * 64];
  const int tid = threadIdx.x;
  const int wid = tid >> 6, lane = tid & 63;
  const int brow = blockIdx.x * 128;   // sample rows
  const int bcol = blockIdx.y * 128;   // hidden cols

  // form A tile: x = theta (+ a_h*k), cast bf16
#pragma unroll 8
  for (int i = 0; i < 32; ++i) {
    int e = tid + i * 256;            // 0..8191 ; row = e/64, d = e%64
    int g = (brow + (e >> 6)) * DDIM + (e & 63);
    float x = theta[g];
    if (use_k) x += a_h * kbuf[g];
    Ax[e] = f2bf(x);
  }
  // stage B tile: contiguous 16KB at W1aT + bcol*64
  {
    const char* gb = (const char*)(W1aT + (size_t)bcol * DDIM);
    char* lb = (char*)Bw;
#pragma unroll
    for (int i = 0; i < 4; ++i) {
      int off = wid * 4096 + i * 1024;
      async_copy16(gb + off + lane * 16, lb + off);
    }
  }
  __syncthreads();

  const int wm = wid >> 1, wn = wid & 1;
  const int lrow = lane & 15, lk = (lane >> 4) * 8;
  f32x4 acc[4][4] = {};
#pragma unroll
  for (int k0 = 0; k0 < 64; k0 += 32) {
    bf16x8 a[4], b[4];
#pragma unroll
    for (int m = 0; m < 4; ++m)
      a[m] = *(const bf16x8*)&Ax[(wm * 64 + m * 16 + lrow) * 64 + k0 + lk];
#pragma unroll
    for (int n = 0; n < 4; ++n)
      b[n] = *(const bf16x8*)&Bw[(wn * 64 + n * 16 + lrow) * 64 + k0 + lk];
#pragma unroll
    for (int m = 0; m < 4; ++m)
#pragma unroll
      for (int n = 0; n < 4; ++n)
        acc[m][n] = __builtin_amdgcn_mfma_f32_16x16x32_bf16(a[m], b[n], acc[m][n], 0, 0, 0);
  }
#pragma unroll
  for (int n = 0; n < 4; ++n) {
    int col = bcol + wn * 64 + n * 16 + lrow;
    float bb = base1[col] + t_s * W1[(size_t)DDIM * HDIM + col];
#pragma unroll
    for (int m = 0; m < 4; ++m) {
      int row0 = brow + wm * 64 + m * 16 + ((lane >> 4) * 4);
#pragma unroll
      for (int q = 0; q < 4; ++q)
        h1[(size_t)(row0 + q) * HDIM + col] = f2bf(tanhf(acc[m][n][q] + bb));
    }
  }
}

// h2 = tanh(h1 @ W2 + b2); A = h1 [8192][1024] bf16, B = W2T [1024][1024] bf16
__global__ __launch_bounds__(256) void k_layer2(
    const u16* __restrict__ h1, const u16* __restrict__ W2T,
    const float* __restrict__ b2, u16* __restrict__ h2) {
  __shared__ u16 Abuf[128 * 32];
  __shared__ u16 Bbuf[128 * 32];
  const int tid = threadIdx.x, wid = tid >> 6, lane = tid & 63;
  const int brow = blockIdx.x * 128, bcol = blockIdx.y * 128;
  const int wm = wid >> 1, wn = wid & 1;
  const int lrow = lane & 15, lk = (lane >> 4) * 8;
  const int srow = lane >> 2;           // 0..15
  const int sbyte = (lane & 3) * 16;    // byte offset within 64B row
  f32x4 acc[4][4] = {};

  for (int k0 = 0; k0 < HDIM; k0 += 32) {
    __syncthreads();
#pragma unroll
    for (int i = 0; i < 2; ++i) {
      int rt = wid * 32 + i * 16;
      async_copy16((const char*)h1 + ((size_t)(brow + rt + srow) * HDIM + k0) * 2 + sbyte,
                   (char*)Abuf + rt * 64);
      async_copy16((const char*)W2T + ((size_t)(bcol + rt + srow) * HDIM + k0) * 2 + sbyte,
                   (char*)Bbuf + rt * 64);
    }
    __syncthreads();
    bf16x8 a[4], b[4];
#pragma unroll
    for (int m = 0; m < 4; ++m)
      a[m] = *(const bf16x8*)&Abuf[(wm * 64 + m * 16 + lrow) * 32 + lk];
#pragma unroll
    for (int n = 0; n < 4; ++n)
      b[n] = *(const bf16x8*)&Bbuf[(wn * 64 + n * 16 + lrow) * 32 + lk];
#pragma unroll
    for (int m = 0; m < 4; ++m)
#pragma unroll
      for (int n = 0; n < 4; ++n)
        acc[m][n] = __builtin_amdgcn_mfma_f32_16x16x32_bf16(a[m], b[n], acc[m][n], 0, 0, 0);
  }
#pragma unroll
  for (int n = 0; n < 4; ++n) {
    int col = bcol + wn * 64 + n * 16 + lrow;
    float bb = b2[col];
#pragma unroll
    for (int m = 0; m < 4; ++m) {
      int row0 = brow + wm * 64 + m * 16 + ((lane >> 4) * 4);
#pragma unroll
      for (int q = 0; q < 4; ++q)
        h2[(size_t)(row0 + q) * HDIM + col] = f2bf(tanhf(acc[m][n][q] + bb));
    }
  }
}

// kpart[kc][8192][64] = h2[:, kc*256:(kc+1)*256] @ W3[kc*256:(kc+1)*256, :]
__global__ __launch_bounds__(256) void k_layer3(
    const u16* __restrict__ h2, const u16* __restrict__ W3T,
    float* __restrict__ kpart) {
  __shared__ u16 Abuf[128 * 32];
  __shared__ u16 Bbuf[64 * 32];
  const int tid = threadIdx.x, wid = tid >> 6, lane = tid & 63;
  const int brow = blockIdx.x * 128;
  const int kc = blockIdx.y;            // 0..3
  const int lrow = lane & 15, lk = (lane >> 4) * 8;
  const int srow = lane >> 2, sbyte = (lane & 3) * 16;
  f32x4 acc[2][4] = {};

  for (int ki = 0; ki < 8; ++ki) {
    int k0 = kc * 256 + ki * 32;
    __syncthreads();
#pragma unroll
    for (int i = 0; i < 2; ++i) {
      int rt = wid * 32 + i * 16;
      async_copy16((const char*)h2 + ((size_t)(brow + rt + srow) * HDIM + k0) * 2 + sbyte,
                   (char*)Abuf + rt * 64);
    }
    {
      int rt = wid * 16;
      async_copy16((const char*)W3T + ((size_t)(rt + srow) * HDIM + k0) * 2 + sbyte,
                   (char*)Bbuf + rt * 64);
    }
    __syncthreads();
    bf16x8 a[2], b[4];
#pragma unroll
    for (int m = 0; m < 2; ++m)
      a[m] = *(const bf16x8*)&Abuf[(wid * 32 + m * 16 + lrow) * 32 + lk];
#pragma unroll
    for (int n = 0; n < 4; ++n)
      b[n] = *(const bf16x8*)&Bbuf[(n * 16 + lrow) * 32 + lk];
#pragma unroll
    for (int m = 0; m < 2; ++m)
#pragma unroll
      for (int n = 0; n < 4; ++n)
        acc[m][n] = __builtin_amdgcn_mfma_f32_16x16x32_bf16(a[m], b[n], acc[m][n], 0, 0, 0);
  }
#pragma unroll
  for (int n = 0; n < 4; ++n) {
    int col = n * 16 + lrow;
#pragma unroll
    for (int m = 0; m < 2; ++m) {
      int row0 = brow + wid * 32 + m * 16 + ((lane >> 4) * 4);
#pragma unroll
      for (int q = 0; q < 4; ++q)
        kpart[(size_t)kc * S_TOT * DDIM + (size_t)(row0 + q) * DDIM + col] = acc[m][n][q];
    }
  }
}

// k = sum(kpart) + b3 ; acc += w*k ; finalize: theta += acc, acc = 0
__global__ __launch_bounds__(256) void k_update(
    const float* __restrict__ kpart, const float* __restrict__ b3,
    float* __restrict__ kbuf, float* __restrict__ acc, float* __restrict__ theta,
    float wgt, int finalize) {
  int i = blockIdx.x * 256 + threadIdx.x;
  const int N = S_TOT * DDIM;
  float kv = kpart[i] + kpart[N + i] + kpart[2 * N + i] + kpart[3 * N + i] + b3[i & 63];
  kbuf[i] = kv;
  float a = acc[i] + wgt * kv;
  if (finalize) { theta[i] += a; acc[i] = 0.f; }
  else          { acc[i] = a; }
}

// ---------------- host ----------------

extern "C" void kernel_launch(void* const* d_in, const int* in_sizes, int n_in,
                              void* d_out, int out_size, void* d_ws, size_t ws_size,
                              hipStream_t stream) {
  const float* theta0 = (const float*)d_in[0];
  const float* ctx    = (const float*)d_in[1];
  const float* W1     = (const float*)d_in[2];
  const float* b1     = (const float*)d_in[3];
  const float* W2     = (const float*)d_in[4];
  const float* b2     = (const float*)d_in[5];
  const float* W3     = (const float*)d_in[6];
  const float* b3     = (const float*)d_in[7];

  char* ws = (char*)d_ws;
  size_t o = 0;
  float* theta = (float*)(ws + o); o += (size_t)S_TOT * DDIM * 4;       // 2 MB
  float* accb  = (float*)(ws + o); o += (size_t)S_TOT * DDIM * 4;       // 2 MB
  float* kbuf  = (float*)(ws + o); o += (size_t)S_TOT * DDIM * 4;       // 2 MB
  float* base1 = (float*)(ws + o); o += 4096;
  u16* h1   = (u16*)(ws + o); o += (size_t)S_TOT * HDIM * 2;            // 16 MB
  u16* h2   = (u16*)(ws + o); o += (size_t)S_TOT * HDIM * 2;            // 16 MB
  u16* W2T  = (u16*)(ws + o); o += (size_t)HDIM * HDIM * 2;             // 2 MB
  u16* W1aT = (u16*)(ws + o); o += (size_t)HDIM * DDIM * 2;             // 128 KB
  u16* W3T  = (u16*)(ws + o); o += (size_t)HDIM * DDIM * 2;             // 128 KB
  float* kpart = (float*)(ws + o); o += (size_t)4 * S_TOT * DDIM * 4;   // 8 MB

  // init state
  hipMemcpyAsync(theta, theta0, (size_t)S_TOT * DDIM * 4, hipMemcpyDeviceToDevice, stream);
  hipMemsetAsync(accb, 0, (size_t)S_TOT * DDIM * 4, stream);

  // precompute: transposed bf16 weights + context-folded layer-1 bias
  k_transpose_cast<<<dim3(16, 16), 256, 0, stream>>>(W2, W2T, HDIM, HDIM); // [1024][1024]
  k_transpose_cast<<<dim3(1, 16), 256, 0, stream>>>(W1, W1aT, DDIM, HDIM); // first 64 rows -> [1024][64]
  k_transpose_cast<<<dim3(16, 1), 256, 0, stream>>>(W3, W3T, HDIM, DDIM);  // [64][1024]
  k_base1<<<dim3(4), 256, 0, stream>>>(W1, b1, ctx, base1);

  const float hstep = 1.0f / (float)NSTEPS;
  const float ah[4] = {0.f, 0.5f * hstep, 0.5f * hstep, hstep};
  const float ct[4] = {0.f, 0.5f, 0.5f, 1.f};
  const float wg[4] = {hstep / 6.f, hstep / 3.f, hstep / 3.f, hstep / 6.f};

  for (int n = 0; n < NSTEPS; ++n) {
    float tn = (float)n * hstep;
    for (int s = 0; s < 4; ++s) {
      k_layer1<<<dim3(64, 8), 256, 0, stream>>>(theta, kbuf, W1aT, W1, base1, h1,
                                                ah[s], tn + ct[s] * hstep, s == 0 ? 0 : 1);
      k_layer2<<<dim3(64, 8), 256, 0, stream>>>(h1, W2T, b2, h2);
      k_layer3<<<dim3(64, 4), 256, 0, stream>>>(h2, W3T, kpart);
      k_update<<<dim3(2048), 256, 0, stream>>>(kpart, b3, kbuf, accb, theta,
                                               wg[s], s == 3 ? 1 : 0);
    }
  }
  hipMemcpyAsync(d_out, theta, (size_t)S_TOT * DDIM * 4, hipMemcpyDeviceToDevice, stream);
}

// Round 2
// 1759.333 us; speedup vs baseline: 1.1714x; 1.1714x over previous
//
#include <hip/hip_runtime.h>

#define S_TOT 8192
#define DDIM  64
#define CDIM  256
#define HDIM  1024
#define NSTEPS 6

typedef unsigned short u16;
typedef unsigned int   u32;
typedef __bf16 bf16x8 __attribute__((ext_vector_type(8)));
typedef float  f32x4  __attribute__((ext_vector_type(4)));

typedef __attribute__((address_space(1))) void gvoid_t;
typedef __attribute__((address_space(3))) void lvoid_t;

__device__ __forceinline__ void async_copy16(const void* g, void* l) {
  __builtin_amdgcn_global_load_lds((gvoid_t*)g, (lvoid_t*)l, 16, 0, 0);
}

__device__ __forceinline__ u16 f2bf(float x) {
  union { float f; u32 u; } v; v.f = x;
  u32 r = v.u + 0x7FFFu + ((v.u >> 16) & 1u);
  return (u16)(r >> 16);
}

// ---------------- precompute kernels ----------------

// out[C][R] = bf16(in[R][C])  (transpose + cast), 64x64 tiles via LDS
__global__ __launch_bounds__(256) void k_transpose_cast(
    const float* __restrict__ in, u16* __restrict__ out, int R, int C) {
  __shared__ float t[64][65];
  int tr = blockIdx.x * 64, tc = blockIdx.y * 64;
  int lr = threadIdx.x >> 6;   // 0..3
  int lc = threadIdx.x & 63;
#pragma unroll
  for (int i = 0; i < 16; ++i) {
    int r = i * 4 + lr;
    int gr = tr + r, gc = tc + lc;
    t[r][lc] = (gr < R && gc < C) ? in[(size_t)gr * C + gc] : 0.f;
  }
  __syncthreads();
#pragma unroll
  for (int i = 0; i < 16; ++i) {
    int c = i * 4 + lr;
    int gc = tc + c, gr = tr + lc;
    if (gc < C && gr < R) out[(size_t)gc * R + gr] = f2bf(t[lc][c]);
  }
}

// base1[j] = b1[j] + sum_c ctx[c] * W1[(65+c)*H + j]
__global__ __launch_bounds__(256) void k_base1(
    const float* __restrict__ W1, const float* __restrict__ b1,
    const float* __restrict__ ctx, float* __restrict__ base1) {
  int j = blockIdx.x * 256 + threadIdx.x;
  float s = b1[j];
  for (int c = 0; c < CDIM; ++c)
    s += ctx[c] * W1[(size_t)(DDIM + 1 + c) * HDIM + j];
  base1[j] = s;
}

// ---------------- layer kernels ----------------

// h1[8192,1024] = tanh( (theta + a_h*kbuf) @ W1a + base1 + t_s*W1t )
__global__ __launch_bounds__(256) void k_layer1(
    const float* __restrict__ theta, const float* __restrict__ kbuf,
    const u16* __restrict__ W1aT, const float* __restrict__ W1,
    const float* __restrict__ base1, u16* __restrict__ h1,
    float a_h, float t_s, int use_k) {
  __shared__ u16 Ax[128 * 64];
  __shared__ u16 Bw[128 * 64];
  const int tid = threadIdx.x;
  const int wid = tid >> 6, lane = tid & 63;
  const int brow = blockIdx.x * 128;   // sample rows
  const int bcol = blockIdx.y * 128;   // hidden cols

#pragma unroll 8
  for (int i = 0; i < 32; ++i) {
    int e = tid + i * 256;
    int g = (brow + (e >> 6)) * DDIM + (e & 63);
    float x = theta[g];
    if (use_k) x += a_h * kbuf[g];
    Ax[e] = f2bf(x);
  }
  {
    const char* gb = (const char*)(W1aT + (size_t)bcol * DDIM);
    char* lb = (char*)Bw;
#pragma unroll
    for (int i = 0; i < 4; ++i) {
      int off = wid * 4096 + i * 1024;
      async_copy16(gb + off + lane * 16, lb + off);
    }
  }
  __syncthreads();

  const int wm = wid >> 1, wn = wid & 1;
  const int lrow = lane & 15, lk = (lane >> 4) * 8;
  f32x4 acc[4][4] = {};
#pragma unroll
  for (int k0 = 0; k0 < 64; k0 += 32) {
    bf16x8 a[4], b[4];
#pragma unroll
    for (int m = 0; m < 4; ++m)
      a[m] = *(const bf16x8*)&Ax[(wm * 64 + m * 16 + lrow) * 64 + k0 + lk];
#pragma unroll
    for (int n = 0; n < 4; ++n)
      b[n] = *(const bf16x8*)&Bw[(wn * 64 + n * 16 + lrow) * 64 + k0 + lk];
#pragma unroll
    for (int m = 0; m < 4; ++m)
#pragma unroll
      for (int n = 0; n < 4; ++n)
        acc[m][n] = __builtin_amdgcn_mfma_f32_16x16x32_bf16(a[m], b[n], acc[m][n], 0, 0, 0);
  }
#pragma unroll
  for (int n = 0; n < 4; ++n) {
    int col = bcol + wn * 64 + n * 16 + lrow;
    float bb = base1[col] + t_s * W1[(size_t)DDIM * HDIM + col];
#pragma unroll
    for (int m = 0; m < 4; ++m) {
      int row0 = brow + wm * 64 + m * 16 + ((lane >> 4) * 4);
#pragma unroll
      for (int q = 0; q < 4; ++q)
        h1[(size_t)(row0 + q) * HDIM + col] = f2bf(tanhf(acc[m][n][q] + bb));
    }
  }
}

// h2 = tanh(h1 @ W2 + b2) — 128x128 tile, BK=64, double-buffered 2-phase
__global__ __launch_bounds__(256) void k_layer2(
    const u16* __restrict__ h1, const u16* __restrict__ W2T,
    const float* __restrict__ b2, u16* __restrict__ h2) {
  __shared__ u16 Abuf[2][128 * 64];
  __shared__ u16 Bbuf[2][128 * 64];
  const int tid = threadIdx.x, wid = tid >> 6, lane = tid & 63;
  const int brow = blockIdx.x * 128, bcol = blockIdx.y * 128;
  const int wm = wid >> 1, wn = wid & 1;
  const int lrow = lane & 15, lk = (lane >> 4) * 8;
  const int srow = tid >> 3;          // 0..31 (row within 32-row stripe)
  const int sbyte = (tid & 7) * 16;   // byte offset within 128B row
  f32x4 acc[4][4] = {};

  auto stage = [&](int buf, int k0) {
#pragma unroll
    for (int i = 0; i < 4; ++i) {
      int r = i * 32 + srow;
      async_copy16((const char*)h1 + ((size_t)(brow + r) * HDIM + k0) * 2 + sbyte,
                   (char*)&Abuf[buf][0] + i * 4096 + tid * 16);
      async_copy16((const char*)W2T + ((size_t)(bcol + r) * HDIM + k0) * 2 + sbyte,
                   (char*)&Bbuf[buf][0] + i * 4096 + tid * 16);
    }
  };

  stage(0, 0);
  __syncthreads();
  int cur = 0;
  for (int t = 0; t < 16; ++t) {
    if (t < 15) stage(cur ^ 1, (t + 1) * 64);  // prefetch next K-tile
    bf16x8 a[4][2], b[4][2];
#pragma unroll
    for (int m = 0; m < 4; ++m)
#pragma unroll
      for (int kk = 0; kk < 2; ++kk)
        a[m][kk] = *(const bf16x8*)&Abuf[cur][(wm * 64 + m * 16 + lrow) * 64 + kk * 32 + lk];
#pragma unroll
    for (int n = 0; n < 4; ++n)
#pragma unroll
      for (int kk = 0; kk < 2; ++kk)
        b[n][kk] = *(const bf16x8*)&Bbuf[cur][(wn * 64 + n * 16 + lrow) * 64 + kk * 32 + lk];
#pragma unroll
    for (int kk = 0; kk < 2; ++kk)
#pragma unroll
      for (int m = 0; m < 4; ++m)
#pragma unroll
        for (int n = 0; n < 4; ++n)
          acc[m][n] = __builtin_amdgcn_mfma_f32_16x16x32_bf16(a[m][kk], b[n][kk], acc[m][n], 0, 0, 0);
    __syncthreads();   // drains vmcnt (next tile staged) + lgkm (reads done)
    cur ^= 1;
  }
#pragma unroll
  for (int n = 0; n < 4; ++n) {
    int col = bcol + wn * 64 + n * 16 + lrow;
    float bb = b2[col];
#pragma unroll
    for (int m = 0; m < 4; ++m) {
      int row0 = brow + wm * 64 + m * 16 + ((lane >> 4) * 4);
#pragma unroll
      for (int q = 0; q < 4; ++q)
        h2[(size_t)(row0 + q) * HDIM + col] = f2bf(tanhf(acc[m][n][q] + bb));
    }
  }
}

// kpart[kc][8192][64] = h2[:, kc*256:(kc+1)*256] @ W3[kc*256:(kc+1)*256, :]
__global__ __launch_bounds__(256) void k_layer3(
    const u16* __restrict__ h2, const u16* __restrict__ W3T,
    float* __restrict__ kpart) {
  __shared__ u16 Abuf[128 * 32];
  __shared__ u16 Bbuf[64 * 32];
  const int tid = threadIdx.x, wid = tid >> 6, lane = tid & 63;
  const int brow = blockIdx.x * 128;
  const int kc = blockIdx.y;            // 0..3
  const int lrow = lane & 15, lk = (lane >> 4) * 8;
  const int srow = lane >> 2, sbyte = (lane & 3) * 16;
  f32x4 acc[2][4] = {};

  for (int ki = 0; ki < 8; ++ki) {
    int k0 = kc * 256 + ki * 32;
    __syncthreads();
#pragma unroll
    for (int i = 0; i < 2; ++i) {
      int rt = wid * 32 + i * 16;
      async_copy16((const char*)h2 + ((size_t)(brow + rt + srow) * HDIM + k0) * 2 + sbyte,
                   (char*)Abuf + rt * 64);
    }
    {
      int rt = wid * 16;
      async_copy16((const char*)W3T + ((size_t)(rt + srow) * HDIM + k0) * 2 + sbyte,
                   (char*)Bbuf + rt * 64);
    }
    __syncthreads();
    bf16x8 a[2], b[4];
#pragma unroll
    for (int m = 0; m < 2; ++m)
      a[m] = *(const bf16x8*)&Abuf[(wid * 32 + m * 16 + lrow) * 32 + lk];
#pragma unroll
    for (int n = 0; n < 4; ++n)
      b[n] = *(const bf16x8*)&Bbuf[(n * 16 + lrow) * 32 + lk];
#pragma unroll
    for (int m = 0; m < 2; ++m)
#pragma unroll
      for (int n = 0; n < 4; ++n)
        acc[m][n] = __builtin_amdgcn_mfma_f32_16x16x32_bf16(a[m], b[n], acc[m][n], 0, 0, 0);
  }
#pragma unroll
  for (int n = 0; n < 4; ++n) {
    int col = n * 16 + lrow;
#pragma unroll
    for (int m = 0; m < 2; ++m) {
      int row0 = brow + wid * 32 + m * 16 + ((lane >> 4) * 4);
#pragma unroll
      for (int q = 0; q < 4; ++q)
        kpart[(size_t)kc * S_TOT * DDIM + (size_t)(row0 + q) * DDIM + col] = acc[m][n][q];
    }
  }
}

// k = sum(kpart) + b3 ; acc += w*k ; finalize: theta += acc, acc = 0
__global__ __launch_bounds__(256) void k_update(
    const float* __restrict__ kpart, const float* __restrict__ b3,
    float* __restrict__ kbuf, float* __restrict__ acc, float* __restrict__ theta,
    float wgt, int finalize) {
  int i = blockIdx.x * 256 + threadIdx.x;
  const int N = S_TOT * DDIM;
  float kv = kpart[i] + kpart[N + i] + kpart[2 * N + i] + kpart[3 * N + i] + b3[i & 63];
  kbuf[i] = kv;
  float a = acc[i] + wgt * kv;
  if (finalize) { theta[i] += a; acc[i] = 0.f; }
  else          { acc[i] = a; }
}

// ---------------- host ----------------

extern "C" void kernel_launch(void* const* d_in, const int* in_sizes, int n_in,
                              void* d_out, int out_size, void* d_ws, size_t ws_size,
                              hipStream_t stream) {
  const float* theta0 = (const float*)d_in[0];
  const float* ctx    = (const float*)d_in[1];
  const float* W1     = (const float*)d_in[2];
  const float* b1     = (const float*)d_in[3];
  const float* W2     = (const float*)d_in[4];
  const float* b2     = (const float*)d_in[5];
  const float* W3     = (const float*)d_in[6];
  const float* b3     = (const float*)d_in[7];

  char* ws = (char*)d_ws;
  size_t o = 0;
  float* theta = (float*)(ws + o); o += (size_t)S_TOT * DDIM * 4;
  float* accb  = (float*)(ws + o); o += (size_t)S_TOT * DDIM * 4;
  float* kbuf  = (float*)(ws + o); o += (size_t)S_TOT * DDIM * 4;
  float* base1 = (float*)(ws + o); o += 4096;
  u16* h1   = (u16*)(ws + o); o += (size_t)S_TOT * HDIM * 2;
  u16* h2   = (u16*)(ws + o); o += (size_t)S_TOT * HDIM * 2;
  u16* W2T  = (u16*)(ws + o); o += (size_t)HDIM * HDIM * 2;
  u16* W1aT = (u16*)(ws + o); o += (size_t)HDIM * DDIM * 2;
  u16* W3T  = (u16*)(ws + o); o += (size_t)HDIM * DDIM * 2;
  float* kpart = (float*)(ws + o); o += (size_t)4 * S_TOT * DDIM * 4;

  hipMemcpyAsync(theta, theta0, (size_t)S_TOT * DDIM * 4, hipMemcpyDeviceToDevice, stream);
  hipMemsetAsync(accb, 0, (size_t)S_TOT * DDIM * 4, stream);

  k_transpose_cast<<<dim3(16, 16), 256, 0, stream>>>(W2, W2T, HDIM, HDIM);
  k_transpose_cast<<<dim3(1, 16), 256, 0, stream>>>(W1, W1aT, DDIM, HDIM);
  k_transpose_cast<<<dim3(16, 1), 256, 0, stream>>>(W3, W3T, HDIM, DDIM);
  k_base1<<<dim3(4), 256, 0, stream>>>(W1, b1, ctx, base1);

  const float hstep = 1.0f / (float)NSTEPS;
  const float ah[4] = {0.f, 0.5f * hstep, 0.5f * hstep, hstep};
  const float ct[4] = {0.f, 0.5f, 0.5f, 1.f};
  const float wg[4] = {hstep / 6.f, hstep / 3.f, hstep / 3.f, hstep / 6.f};

  for (int n = 0; n < NSTEPS; ++n) {
    float tn = (float)n * hstep;
    for (int s = 0; s < 4; ++s) {
      k_layer1<<<dim3(64, 8), 256, 0, stream>>>(theta, kbuf, W1aT, W1, base1, h1,
                                                ah[s], tn + ct[s] * hstep, s == 0 ? 0 : 1);
      k_layer2<<<dim3(64, 8), 256, 0, stream>>>(h1, W2T, b2, h2);
      k_layer3<<<dim3(64, 4), 256, 0, stream>>>(h2, W3T, kpart);
      k_update<<<dim3(2048), 256, 0, stream>>>(kpart, b3, kbuf, accb, theta,
                                               wg[s], s == 3 ? 1 : 0);
    }
  }
  hipMemcpyAsync(d_out, theta, (size_t)S_TOT * DDIM * 4, hipMemcpyDeviceToDevice, stream);
}

// Round 3
// 1383.110 us; speedup vs baseline: 1.4900x; 1.2720x over previous
//
#include <hip/hip_runtime.h>

#define S_TOT 8192
#define DDIM  64
#define CDIM  256
#define HDIM  1024
#define NSTEPS 6

typedef unsigned short u16;
typedef unsigned int   u32;
typedef __bf16 bf16x8 __attribute__((ext_vector_type(8)));
typedef float  f32x4  __attribute__((ext_vector_type(4)));

typedef __attribute__((address_space(1))) void gvoid_t;
typedef __attribute__((address_space(3))) void lvoid_t;

__device__ __forceinline__ void async_copy16(const void* g, void* l) {
  __builtin_amdgcn_global_load_lds((gvoid_t*)g, (lvoid_t*)l, 16, 0, 0);
}

__device__ __forceinline__ u16 f2bf(float x) {
  union { float f; u32 u; } v; v.f = x;
  u32 r = v.u + 0x7FFFu + ((v.u >> 16) & 1u);
  return (u16)(r >> 16);
}

// ---------------- precompute kernels ----------------

__global__ __launch_bounds__(256) void k_transpose_cast(
    const float* __restrict__ in, u16* __restrict__ out, int R, int C) {
  __shared__ float t[64][65];
  int tr = blockIdx.x * 64, tc = blockIdx.y * 64;
  int lr = threadIdx.x >> 6;
  int lc = threadIdx.x & 63;
#pragma unroll
  for (int i = 0; i < 16; ++i) {
    int r = i * 4 + lr;
    int gr = tr + r, gc = tc + lc;
    t[r][lc] = (gr < R && gc < C) ? in[(size_t)gr * C + gc] : 0.f;
  }
  __syncthreads();
#pragma unroll
  for (int i = 0; i < 16; ++i) {
    int c = i * 4 + lr;
    int gc = tc + c, gr = tr + lc;
    if (gc < C && gr < R) out[(size_t)gc * R + gr] = f2bf(t[lc][c]);
  }
}

__global__ __launch_bounds__(256) void k_base1(
    const float* __restrict__ W1, const float* __restrict__ b1,
    const float* __restrict__ ctx, float* __restrict__ base1) {
  int j = blockIdx.x * 256 + threadIdx.x;
  float s = b1[j];
  for (int c = 0; c < CDIM; ++c)
    s += ctx[c] * W1[(size_t)(DDIM + 1 + c) * HDIM + j];
  base1[j] = s;
}

// ---------------- layer kernels ----------------

__global__ __launch_bounds__(256) void k_layer1(
    const float* __restrict__ theta, const float* __restrict__ kbuf,
    const u16* __restrict__ W1aT, const float* __restrict__ W1,
    const float* __restrict__ base1, u16* __restrict__ h1,
    float a_h, float t_s, int use_k) {
  __shared__ u16 Ax[128 * 64];
  __shared__ u16 Bw[128 * 64];
  const int tid = threadIdx.x;
  const int wid = tid >> 6, lane = tid & 63;
  const int brow = blockIdx.x * 128;
  const int bcol = blockIdx.y * 128;

#pragma unroll 8
  for (int i = 0; i < 32; ++i) {
    int e = tid + i * 256;
    int g = (brow + (e >> 6)) * DDIM + (e & 63);
    float x = theta[g];
    if (use_k) x += a_h * kbuf[g];
    Ax[e] = f2bf(x);
  }
  {
    const char* gb = (const char*)(W1aT + (size_t)bcol * DDIM);
    char* lb = (char*)Bw;
#pragma unroll
    for (int i = 0; i < 4; ++i) {
      int off = wid * 4096 + i * 1024;
      async_copy16(gb + off + lane * 16, lb + off);
    }
  }
  __syncthreads();

  const int wm = wid >> 1, wn = wid & 1;
  const int lrow = lane & 15, lk = (lane >> 4) * 8;
  f32x4 acc[4][4] = {};
#pragma unroll
  for (int k0 = 0; k0 < 64; k0 += 32) {
    bf16x8 a[4], b[4];
#pragma unroll
    for (int m = 0; m < 4; ++m)
      a[m] = *(const bf16x8*)&Ax[(wm * 64 + m * 16 + lrow) * 64 + k0 + lk];
#pragma unroll
    for (int n = 0; n < 4; ++n)
      b[n] = *(const bf16x8*)&Bw[(wn * 64 + n * 16 + lrow) * 64 + k0 + lk];
#pragma unroll
    for (int m = 0; m < 4; ++m)
#pragma unroll
      for (int n = 0; n < 4; ++n)
        acc[m][n] = __builtin_amdgcn_mfma_f32_16x16x32_bf16(a[m], b[n], acc[m][n], 0, 0, 0);
  }
#pragma unroll
  for (int n = 0; n < 4; ++n) {
    int col = bcol + wn * 64 + n * 16 + lrow;
    float bb = base1[col] + t_s * W1[(size_t)DDIM * HDIM + col];
#pragma unroll
    for (int m = 0; m < 4; ++m) {
      int row0 = brow + wm * 64 + m * 16 + ((lane >> 4) * 4);
#pragma unroll
      for (int q = 0; q < 4; ++q)
        h1[(size_t)(row0 + q) * HDIM + col] = f2bf(tanhf(acc[m][n][q] + bb));
    }
  }
}

// h2 = tanh(h1 @ W2 + b2)
// 128x128 tile, BK=64, 8 waves (2Mx4N, wave-tile 64x32), double-buffered
// 2-phase, T2 XOR-swizzle (both sides: pre-swizzled global src + swizzled
// ds_read; LDS dest stays linear for global_load_lds).
__global__ __launch_bounds__(512, 4) void k_layer2(
    const u16* __restrict__ h1, const u16* __restrict__ W2T,
    const float* __restrict__ b2, u16* __restrict__ h2) {
  __shared__ u16 Abuf[2][128 * 64];
  __shared__ u16 Bbuf[2][128 * 64];
  const int tid = threadIdx.x, wid = tid >> 6, lane = tid & 63;
  const int brow = blockIdx.x * 128, bcol = blockIdx.y * 128;
  const int wm = wid >> 2, wn = wid & 3;       // 2 x 4 wave grid
  const int lrow = lane & 15, lk4 = lane >> 4; // frag row / k-slot part
  const int srow = tid >> 3;                   // 0..63 (stage row in half)
  const int slot = tid & 7;                    // 16B slot within 128B row
  f32x4 acc[4][2] = {};

  auto stage = [&](int buf, int k0) {
#pragma unroll
    for (int i = 0; i < 2; ++i) {
      int row = i * 64 + srow;
      int ksl = slot ^ (row & 7);              // pre-swizzled source slot
      async_copy16((const char*)h1 + ((size_t)(brow + row) * HDIM + k0 + ksl * 8) * 2,
                   (char*)&Abuf[buf][0] + i * 8192 + tid * 16);
      async_copy16((const char*)W2T + ((size_t)(bcol + row) * HDIM + k0 + ksl * 8) * 2,
                   (char*)&Bbuf[buf][0] + i * 8192 + tid * 16);
    }
  };

  stage(0, 0);
  __syncthreads();
  int cur = 0;
  for (int t = 0; t < 16; ++t) {
    if (t < 15) stage(cur ^ 1, (t + 1) * 64);  // prefetch next K-tile
    bf16x8 a[4][2], b[2][2];
#pragma unroll
    for (int m = 0; m < 4; ++m)
#pragma unroll
      for (int kk = 0; kk < 2; ++kk) {
        int row = wm * 64 + m * 16 + lrow;
        int byte = row * 128 + (((kk * 4 + lk4) ^ (row & 7)) << 4);
        a[m][kk] = *(const bf16x8*)((const char*)&Abuf[cur][0] + byte);
      }
#pragma unroll
    for (int n = 0; n < 2; ++n)
#pragma unroll
      for (int kk = 0; kk < 2; ++kk) {
        int row = wn * 32 + n * 16 + lrow;
        int byte = row * 128 + (((kk * 4 + lk4) ^ (row & 7)) << 4);
        b[n][kk] = *(const bf16x8*)((const char*)&Bbuf[cur][0] + byte);
      }
#pragma unroll
    for (int kk = 0; kk < 2; ++kk)
#pragma unroll
      for (int m = 0; m < 4; ++m)
#pragma unroll
        for (int n = 0; n < 2; ++n)
          acc[m][n] = __builtin_amdgcn_mfma_f32_16x16x32_bf16(a[m][kk], b[n][kk], acc[m][n], 0, 0, 0);
    __syncthreads();   // drains vmcnt (next tile landed) + lgkm
    cur ^= 1;
  }
#pragma unroll
  for (int n = 0; n < 2; ++n) {
    int col = bcol + wn * 32 + n * 16 + lrow;
    float bb = b2[col];
#pragma unroll
    for (int m = 0; m < 4; ++m) {
      int row0 = brow + wm * 64 + m * 16 + ((lane >> 4) * 4);
#pragma unroll
      for (int q = 0; q < 4; ++q)
        h2[(size_t)(row0 + q) * HDIM + col] = f2bf(tanhf(acc[m][n][q] + bb));
    }
  }
}

// kpart[kc][8192][64] = h2[:, kc*256:(kc+1)*256] @ W3[kc*256:(kc+1)*256, :]
__global__ __launch_bounds__(256) void k_layer3(
    const u16* __restrict__ h2, const u16* __restrict__ W3T,
    float* __restrict__ kpart) {
  __shared__ u16 Abuf[128 * 32];
  __shared__ u16 Bbuf[64 * 32];
  const int tid = threadIdx.x, wid = tid >> 6, lane = tid & 63;
  const int brow = blockIdx.x * 128;
  const int kc = blockIdx.y;
  const int lrow = lane & 15, lk = (lane >> 4) * 8;
  const int srow = lane >> 2, sbyte = (lane & 3) * 16;
  f32x4 acc[2][4] = {};

  for (int ki = 0; ki < 8; ++ki) {
    int k0 = kc * 256 + ki * 32;
    __syncthreads();
#pragma unroll
    for (int i = 0; i < 2; ++i) {
      int rt = wid * 32 + i * 16;
      async_copy16((const char*)h2 + ((size_t)(brow + rt + srow) * HDIM + k0) * 2 + sbyte,
                   (char*)Abuf + rt * 64);
    }
    {
      int rt = wid * 16;
      async_copy16((const char*)W3T + ((size_t)(rt + srow) * HDIM + k0) * 2 + sbyte,
                   (char*)Bbuf + rt * 64);
    }
    __syncthreads();
    bf16x8 a[2], b[4];
#pragma unroll
    for (int m = 0; m < 2; ++m)
      a[m] = *(const bf16x8*)&Abuf[(wid * 32 + m * 16 + lrow) * 32 + lk];
#pragma unroll
    for (int n = 0; n < 4; ++n)
      b[n] = *(const bf16x8*)&Bbuf[(n * 16 + lrow) * 32 + lk];
#pragma unroll
    for (int m = 0; m < 2; ++m)
#pragma unroll
      for (int n = 0; n < 4; ++n)
        acc[m][n] = __builtin_amdgcn_mfma_f32_16x16x32_bf16(a[m], b[n], acc[m][n], 0, 0, 0);
  }
#pragma unroll
  for (int n = 0; n < 4; ++n) {
    int col = n * 16 + lrow;
#pragma unroll
    for (int m = 0; m < 2; ++m) {
      int row0 = brow + wid * 32 + m * 16 + ((lane >> 4) * 4);
#pragma unroll
      for (int q = 0; q < 4; ++q)
        kpart[(size_t)kc * S_TOT * DDIM + (size_t)(row0 + q) * DDIM + col] = acc[m][n][q];
    }
  }
}

__global__ __launch_bounds__(256) void k_update(
    const float* __restrict__ kpart, const float* __restrict__ b3,
    float* __restrict__ kbuf, float* __restrict__ acc, float* __restrict__ theta,
    float wgt, int finalize) {
  int i = blockIdx.x * 256 + threadIdx.x;
  const int N = S_TOT * DDIM;
  float kv = kpart[i] + kpart[N + i] + kpart[2 * N + i] + kpart[3 * N + i] + b3[i & 63];
  kbuf[i] = kv;
  float a = acc[i] + wgt * kv;
  if (finalize) { theta[i] += a; acc[i] = 0.f; }
  else          { acc[i] = a; }
}

// ---------------- host ----------------

extern "C" void kernel_launch(void* const* d_in, const int* in_sizes, int n_in,
                              void* d_out, int out_size, void* d_ws, size_t ws_size,
                              hipStream_t stream) {
  const float* theta0 = (const float*)d_in[0];
  const float* ctx    = (const float*)d_in[1];
  const float* W1     = (const float*)d_in[2];
  const float* b1     = (const float*)d_in[3];
  const float* W2     = (const float*)d_in[4];
  const float* b2     = (const float*)d_in[5];
  const float* W3     = (const float*)d_in[6];
  const float* b3     = (const float*)d_in[7];

  char* ws = (char*)d_ws;
  size_t o = 0;
  float* theta = (float*)(ws + o); o += (size_t)S_TOT * DDIM * 4;
  float* accb  = (float*)(ws + o); o += (size_t)S_TOT * DDIM * 4;
  float* kbuf  = (float*)(ws + o); o += (size_t)S_TOT * DDIM * 4;
  float* base1 = (float*)(ws + o); o += 4096;
  u16* h1   = (u16*)(ws + o); o += (size_t)S_TOT * HDIM * 2;
  u16* h2   = (u16*)(ws + o); o += (size_t)S_TOT * HDIM * 2;
  u16* W2T  = (u16*)(ws + o); o += (size_t)HDIM * HDIM * 2;
  u16* W1aT = (u16*)(ws + o); o += (size_t)HDIM * DDIM * 2;
  u16* W3T  = (u16*)(ws + o); o += (size_t)HDIM * DDIM * 2;
  float* kpart = (float*)(ws + o); o += (size_t)4 * S_TOT * DDIM * 4;

  hipMemcpyAsync(theta, theta0, (size_t)S_TOT * DDIM * 4, hipMemcpyDeviceToDevice, stream);
  hipMemsetAsync(accb, 0, (size_t)S_TOT * DDIM * 4, stream);

  k_transpose_cast<<<dim3(16, 16), 256, 0, stream>>>(W2, W2T, HDIM, HDIM);
  k_transpose_cast<<<dim3(1, 16), 256, 0, stream>>>(W1, W1aT, DDIM, HDIM);
  k_transpose_cast<<<dim3(16, 1), 256, 0, stream>>>(W3, W3T, HDIM, DDIM);
  k_base1<<<dim3(4), 256, 0, stream>>>(W1, b1, ctx, base1);

  const float hstep = 1.0f / (float)NSTEPS;
  const float ah[4] = {0.f, 0.5f * hstep, 0.5f * hstep, hstep};
  const float ct[4] = {0.f, 0.5f, 0.5f, 1.f};
  const float wg[4] = {hstep / 6.f, hstep / 3.f, hstep / 3.f, hstep / 6.f};

  for (int n = 0; n < NSTEPS; ++n) {
    float tn = (float)n * hstep;
    for (int s = 0; s < 4; ++s) {
      k_layer1<<<dim3(64, 8), 256, 0, stream>>>(theta, kbuf, W1aT, W1, base1, h1,
                                                ah[s], tn + ct[s] * hstep, s == 0 ? 0 : 1);
      k_layer2<<<dim3(64, 8), 512, 0, stream>>>(h1, W2T, b2, h2);
      k_layer3<<<dim3(64, 4), 256, 0, stream>>>(h2, W3T, kpart);
      k_update<<<dim3(2048), 256, 0, stream>>>(kpart, b3, kbuf, accb, theta,
                                               wg[s], s == 3 ? 1 : 0);
    }
  }
  hipMemcpyAsync(d_out, theta, (size_t)S_TOT * DDIM * 4, hipMemcpyDeviceToDevice, stream);
}